// Round 9
// baseline (35.688 us; speedup 1.0000x reference)
//
#include <hip/hip_runtime.h>

// out[b,s,e] = W_e[e, tokens[b,s]] + W_p[s,e]
// tokens: (2,2048) int32 ; W_e: (1024,32000) f32 ; W_p: (2048,1024) f32
// out: (2,2048,1024) f32
//
// Round 8 (fixed): round 7 (VC=256, 64x256 tile, 512 thr, 2 blocks/CU,
// lgkmcnt-only barriers, issue-next-tile-during-scatter) plus:
//  (a) CONSECUTIVE vocab-chunk ownership: block bx owns cv = 4*bx+j -> per
//      e-row the j-loop reads four adjacent 1 KB segments = 4 KB sequential
//      DRAM runs.
//  (b) Non-temporal W_e loads + out stores (read-once / write-once data),
//      via a native ext_vector_type alias (HIP_vector_type isn't accepted
//      by the nontemporal builtins).

#define VOCAB 32000
#define EDIM  1024
#define SLEN  2048
#define NBS   4096            // B*S
#define VC    256             // vocab chunk width (1 KB row segment)
#define NV    (VOCAB / VC)    // 125 vocab chunks
#define EC    64              // e chunk height
#define NE    (EDIM / EC)     // 16
#define GX    32              // block bx owns cv = 4*bx + j
#define MAXJ  4               // bx<31: 4 tiles; bx=31: 1 tile (125 = 31*4+1)
#define LCAP  160             // per-chunk token list capacity (mean 32.8)
#define NTHR  512

typedef float vf4 __attribute__((ext_vector_type(4)));   // native vec for nt builtins

#define LDS_BARRIER() asm volatile("s_waitcnt lgkmcnt(0)\n\ts_barrier" ::: "memory")

__global__ __launch_bounds__(NTHR) void fused_embed_kernel(
    const int*   __restrict__ tokens,
    const float* __restrict__ W_e,
    const float* __restrict__ W_p,
    float*       __restrict__ out)
{
    __shared__ float tileT[VC][EC + 1];    // transposed; scatter reads conflict-free
    __shared__ int   list[MAXJ][LCAP];
    __shared__ int   cnts[MAXJ];

    const int bx     = blockIdx.x;         // 0..31
    const int ce     = blockIdx.y;         // 0..15
    const int e0     = ce * EC;
    const int t      = threadIdx.x;        // 0..511
    const int lane64 = t & 63;             // 64 lanes x float4 = 1 KB row segment
    const int r0     = t >> 6;             // 0..7 (row phase)

    if (t < MAXJ) cnts[t] = 0;
    __syncthreads();                       // free: nothing outstanding

    const int jmax = (bx < GX - 1) ? MAXJ : (NV - (GX - 1) * MAXJ); // 4 or 1

    // ---- issue tile j=0 (cv = 4*bx); 1 KB contiguous per wave-instr ----
    vf4 vbuf[8];
    {
        const size_t v0 = (size_t)(bx * MAXJ) * VC;
        #pragma unroll
        for (int rr = 0; rr < 8; ++rr)
            vbuf[rr] = __builtin_nontemporal_load(
                reinterpret_cast<const vf4*>(
                    &W_e[(size_t)(e0 + rr * 8 + r0) * VOCAB + v0 + lane64 * 4]));
    }

    // ---- scan all tokens once, bucketing into this block's chunks ----
    #pragma unroll
    for (int k = 0; k < NBS / NTHR; ++k) { // 8 iterations
        const int bs  = k * NTHR + t;      // coalesced; L2-hot
        const int tok = tokens[bs];
        const int cv  = tok >> 8;          // vocab chunk (VC=256), 0..124
        if ((cv >> 2) == bx) {
            const int j    = cv & 3;       // consecutive ownership
            const int slot = atomicAdd(&cnts[j], 1);
            if (slot < LCAP)
                list[j][slot] = bs | ((tok & (VC - 1)) << 12);  // 12+8 bits
        }
    }
    __syncthreads();                       // publish lists (tile-0 ~arrived)

    const int q   = (t & 63) >> 4;         // quarter-wave 0..3
    const int l16 = t & 15;
    const int w   = t >> 6;                // wave 0..7

    for (int j = 0; j < MAXJ; ++j) {
        if (j >= jmax) break;              // block-uniform

        // ---- commit vbuf -> tileT (waits only this tile's arrivals) ----
        #pragma unroll
        for (int rr = 0; rr < 8; ++rr) {
            const int row = rr * 8 + r0;
            tileT[lane64 * 4 + 0][row] = vbuf[rr].x;
            tileT[lane64 * 4 + 1][row] = vbuf[rr].y;
            tileT[lane64 * 4 + 2][row] = vbuf[rr].z;
            tileT[lane64 * 4 + 3][row] = vbuf[rr].w;
        }
        LDS_BARRIER();                     // tile visible; vmcnt NOT drained

        // ---- issue tile j+1 (ADJACENT 1 KB in each row: sequential runs) ----
        if (j + 1 < jmax) {
            const size_t v0 = (size_t)(bx * MAXJ + j + 1) * VC;
            #pragma unroll
            for (int rr = 0; rr < 8; ++rr)
                vbuf[rr] = __builtin_nontemporal_load(
                    reinterpret_cast<const vf4*>(
                        &W_e[(size_t)(e0 + rr * 8 + r0) * VOCAB + v0 + lane64 * 4]));
        }

        // ---- scatter tile j: quarter-wave per token, float4 everywhere ----
        int nt = cnts[j];
        if (nt > LCAP) nt = LCAP;          // safety clamp (unreachable)
        const int ngroups = (nt + 3) >> 2;
        for (int g = w; g < ngroups; g += 8) {
            const int slot = g * 4 + q;
            if (slot < nt) {
                const int entry = list[j][slot];
                const int bs    = entry & 0xFFF;
                const int col   = entry >> 12;
                const int s     = bs & (SLEN - 1);
                // tileT read: bank = (col + 4*l16 + k) % 32, worst 2-way (free)
                const float v0 = tileT[col][l16 * 4 + 0];
                const float v1 = tileT[col][l16 * 4 + 1];
                const float v2 = tileT[col][l16 * 4 + 2];
                const float v3 = tileT[col][l16 * 4 + 3];
                const vf4 wp = *reinterpret_cast<const vf4*>(
                    &W_p[(size_t)s * EDIM + e0 + l16 * 4]);
                vf4 r;
                r.x = v0 + wp.x; r.y = v1 + wp.y; r.z = v2 + wp.z; r.w = v3 + wp.w;
                __builtin_nontemporal_store(r,
                    reinterpret_cast<vf4*>(&out[(size_t)bs * EDIM + e0 + l16 * 4]));
            }
        }
        LDS_BARRIER();                     // scatter done; j+1 loads in flight
    }
}

extern "C" void kernel_launch(void* const* d_in, const int* in_sizes, int n_in,
                              void* d_out, int out_size, void* d_ws, size_t ws_size,
                              hipStream_t stream) {
    const int*   tokens = (const int*)d_in[0];
    const float* W_e    = (const float*)d_in[1];
    const float* W_p    = (const float*)d_in[2];
    float*       out    = (float*)d_out;

    dim3 grid(GX, NE);                     // 32 x 16 = 512 blocks, 2/CU (LDS-limited)
    fused_embed_kernel<<<grid, NTHR, 0, stream>>>(tokens, W_e, W_p, out);
}

// Round 10
// 34.726 us; speedup vs baseline: 1.0277x; 1.0277x over previous
//
#include <hip/hip_runtime.h>

// out[b,s,e] = W_e[e, tokens[b,s]] + W_p[s,e]
// tokens: (2,2048) int32 ; W_e: (1024,32000) f32 ; W_p: (2048,1024) f32
// out: (2,2048,1024) f32
//
// Round 10 = round 7 structure (VC=256 1KB-granule loads, cv = bx + 32*j so
// co-running blocks read ADJACENT segments, lgkmcnt-only barriers,
// issue-next-tile-during-scatter, NO nontemporal) with ONE change:
// EC 64->32 (tile 32x256 f32 = 33 KB LDS) -> 4 blocks/CU x 256 threads.
// Same waves/CU and same in-flight bytes/CU, but 4 independent load streams
// per CU (vs 2) and half-length commit/scatter critical sections.

#define VOCAB 32000
#define EDIM  1024
#define SLEN  2048
#define NBS   4096            // B*S
#define VC    256             // vocab chunk width (1 KB row segment)
#define NV    (VOCAB / VC)    // 125 vocab chunks
#define EC    32              // e chunk height
#define NE    (EDIM / EC)     // 32
#define GX    32              // block bx handles cv = bx + 32*j
#define MAXJ  4               // bx<29: 4 tiles, bx>=29: 3 (29*4+3*3=125)
#define LCAP  160             // per-chunk token list capacity (mean 32.8)
#define NTHR  256

#define LDS_BARRIER() asm volatile("s_waitcnt lgkmcnt(0)\n\ts_barrier" ::: "memory")

__global__ __launch_bounds__(NTHR) void fused_embed_kernel(
    const int*   __restrict__ tokens,
    const float* __restrict__ W_e,
    const float* __restrict__ W_p,
    float*       __restrict__ out)
{
    __shared__ float tileT[VC][EC + 1];    // transposed; stride 33 (~bank+1)
    __shared__ int   list[MAXJ][LCAP];
    __shared__ int   cnts[MAXJ];

    const int bx     = blockIdx.x;         // 0..31
    const int ce     = blockIdx.y;         // 0..31
    const int e0     = ce * EC;
    const int t      = threadIdx.x;        // 0..255
    const int lane64 = t & 63;             // 64 lanes x float4 = 1 KB row segment
    const int r0     = t >> 6;             // 0..3 (row phase)

    if (t < MAXJ) cnts[t] = 0;
    __syncthreads();                       // free: nothing outstanding

    const int jmax = (bx < NV - GX * (MAXJ - 1)) ? MAXJ : (MAXJ - 1); // bx<29 ? 4 : 3

    // ---- issue tile j=0: 8 x float4/thread, each wave-instr = 1 KB one-row ----
    float4 vbuf[8];
    {
        const size_t v0 = (size_t)bx * VC;
        #pragma unroll
        for (int rr = 0; rr < 8; ++rr)
            vbuf[rr] = *reinterpret_cast<const float4*>(
                &W_e[(size_t)(e0 + rr * 4 + r0) * VOCAB + v0 + lane64 * 4]);
    }

    // ---- scan all tokens once, bucketing into this block's chunks ----
    #pragma unroll
    for (int k = 0; k < NBS / NTHR; ++k) { // 16 iterations; L2-hot
        const int bs  = k * NTHR + t;      // coalesced
        const int tok = tokens[bs];
        const int cv  = tok >> 8;          // vocab chunk (VC=256), 0..124
        if ((cv & (GX - 1)) == bx) {
            const int j    = cv >> 5;      // which of this block's tiles
            const int slot = atomicAdd(&cnts[j], 1);
            if (slot < LCAP)
                list[j][slot] = bs | ((tok & (VC - 1)) << 12);  // 12+8 bits
        }
    }
    __syncthreads();                       // publish lists (tile-0 ~arrived)

    const int oct = (t & 63) >> 3;         // 8-lane group 0..7
    const int l8  = t & 7;
    const int w   = t >> 6;                // wave 0..3

    for (int j = 0; j < MAXJ; ++j) {
        if (j >= jmax) break;              // block-uniform

        // ---- commit vbuf -> tileT (waits only this tile's arrivals) ----
        // 8-way bank conflict on write, accepted: hidden under load waits.
        #pragma unroll
        for (int rr = 0; rr < 8; ++rr) {
            const int row = rr * 4 + r0;
            tileT[lane64 * 4 + 0][row] = vbuf[rr].x;
            tileT[lane64 * 4 + 1][row] = vbuf[rr].y;
            tileT[lane64 * 4 + 2][row] = vbuf[rr].z;
            tileT[lane64 * 4 + 3][row] = vbuf[rr].w;
        }
        LDS_BARRIER();                     // tile visible; vmcnt NOT drained

        // ---- issue tile j+1 (co-running blocks stay address-adjacent) ----
        if (j + 1 < jmax) {
            const size_t v0 = (size_t)(bx + GX * (j + 1)) * VC;
            #pragma unroll
            for (int rr = 0; rr < 8; ++rr)
                vbuf[rr] = *reinterpret_cast<const float4*>(
                    &W_e[(size_t)(e0 + rr * 4 + r0) * VOCAB + v0 + lane64 * 4]);
        }

        // ---- scatter tile j: 8-lane group per token, float4 everywhere ----
        int nt = cnts[j];
        if (nt > LCAP) nt = LCAP;          // safety clamp (unreachable)
        const int ngroups = (nt + 7) >> 3;
        for (int g = w; g < ngroups; g += 4) {
            const int slot = g * 8 + oct;
            if (slot < nt) {
                const int entry = list[j][slot];
                const int bs    = entry & 0xFFF;
                const int col   = entry >> 12;
                const int s     = bs & (SLEN - 1);
                // tileT read: bank = (col + 4*l8 + k) % 32; groups pigeonhole
                // into 4 residue classes -> typical 2-way (free, m136)
                const float v0 = tileT[col][l8 * 4 + 0];
                const float v1 = tileT[col][l8 * 4 + 1];
                const float v2 = tileT[col][l8 * 4 + 2];
                const float v3 = tileT[col][l8 * 4 + 3];
                const float4 wp = *reinterpret_cast<const float4*>(
                    &W_p[(size_t)s * EDIM + e0 + l8 * 4]);
                float4 r;
                r.x = v0 + wp.x; r.y = v1 + wp.y; r.z = v2 + wp.z; r.w = v3 + wp.w;
                *reinterpret_cast<float4*>(
                    &out[(size_t)bs * EDIM + e0 + l8 * 4]) = r;
            }
        }
        LDS_BARRIER();                     // scatter done; j+1 loads in flight
    }
}

extern "C" void kernel_launch(void* const* d_in, const int* in_sizes, int n_in,
                              void* d_out, int out_size, void* d_ws, size_t ws_size,
                              hipStream_t stream) {
    const int*   tokens = (const int*)d_in[0];
    const float* W_e    = (const float*)d_in[1];
    const float* W_p    = (const float*)d_in[2];
    float*       out    = (float*)d_out;

    dim3 grid(GX, NE);                     // 32 x 32 = 1024 blocks, 4/CU
    fused_embed_kernel<<<grid, NTHR, 0, stream>>>(tokens, W_e, W_p, out);
}

// Round 11
// 33.115 us; speedup vs baseline: 1.0777x; 1.0486x over previous
//
#include <hip/hip_runtime.h>

// out[b,s,e] = W_e[e, tokens[b,s]] + W_p[s,e]
// tokens: (2,2048) int32 ; W_e: (1024,32000) f32 ; W_p: (2048,1024) f32
// out: (2,2048,1024) f32
//
// Best-measured configuration (round 7, 32.6 us): VC=256 -> every
// wave-instruction reads ONE contiguous 1 KB row segment; co-running blocks
// (bx=0..31, same ce) read ADJACENT segments simultaneously. Tile 64x256 f32
// (66.6 KB LDS, transposed, stride 65), 2 blocks/CU x 512 threads. Single
// register buffer, issue-next-tile-during-scatter, lgkmcnt-only barriers so
// next-tile global loads stay in flight across commit/scatter.

#define VOCAB 32000
#define EDIM  1024
#define SLEN  2048
#define NBS   4096            // B*S
#define VC    256             // vocab chunk width (1 KB row segment)
#define NV    (VOCAB / VC)    // 125 vocab chunks
#define EC    64              // e chunk height
#define NE    (EDIM / EC)     // 16
#define GX    32              // block bx handles cv = bx + 32*j
#define MAXJ  4               // bx<29: 4 tiles, bx>=29: 3  (29*4+3*3=125)
#define LCAP  160             // per-chunk token list capacity (mean 32.8)
#define NTHR  512

#define LDS_BARRIER() asm volatile("s_waitcnt lgkmcnt(0)\n\ts_barrier" ::: "memory")

__global__ __launch_bounds__(NTHR) void fused_embed_kernel(
    const int*   __restrict__ tokens,
    const float* __restrict__ W_e,
    const float* __restrict__ W_p,
    float*       __restrict__ out)
{
    __shared__ float tileT[VC][EC + 1];    // transposed; scatter reads conflict-free
    __shared__ int   list[MAXJ][LCAP];
    __shared__ int   cnts[MAXJ];

    const int bx     = blockIdx.x;         // 0..31
    const int ce     = blockIdx.y;         // 0..15
    const int e0     = ce * EC;
    const int t      = threadIdx.x;        // 0..511
    const int lane64 = t & 63;             // 64 lanes x float4 = 1 KB row segment
    const int r0     = t >> 6;             // 0..7 (row phase)

    if (t < MAXJ) cnts[t] = 0;
    __syncthreads();                       // free: nothing outstanding

    const int jmax = (bx < NV - GX * (MAXJ - 1)) ? MAXJ : (MAXJ - 1); // bx<29 ? 4 : 3

    // ---- issue tile 0 (8 x float4/thread, each wave-instr = 1 KB one-row) ----
    float4 vbuf[8];
    {
        const size_t v0 = (size_t)bx * VC;
        #pragma unroll
        for (int rr = 0; rr < 8; ++rr)
            vbuf[rr] = *reinterpret_cast<const float4*>(
                &W_e[(size_t)(e0 + rr * 8 + r0) * VOCAB + v0 + lane64 * 4]);
    }

    // ---- scan all tokens once, bucketing into this block's chunks ----
    #pragma unroll
    for (int k = 0; k < NBS / NTHR; ++k) { // 8 iterations
        const int bs  = k * NTHR + t;      // coalesced; L2-hot
        const int tok = tokens[bs];
        const int cv  = tok >> 8;          // vocab chunk (VC=256)
        if ((cv & (GX - 1)) == bx) {
            const int j    = cv >> 5;      // which of this block's tiles
            const int slot = atomicAdd(&cnts[j], 1);
            if (slot < LCAP)
                list[j][slot] = bs | ((tok & (VC - 1)) << 12);  // 12+8 bits
        }
    }
    __syncthreads();                       // publish lists (tile-0 loads ~arrived)

    const int q   = (t & 63) >> 4;         // quarter-wave 0..3
    const int l16 = t & 15;
    const int w   = t >> 6;                // wave 0..7

    for (int j = 0; j < MAXJ; ++j) {
        if (j >= jmax) break;              // block-uniform

        // ---- commit vbuf -> tileT (waits only this tile's arrivals) ----
        // bank = (4*lane64 + c + 8*rr + r0) % 32 -> 8-way conflict, accepted:
        // LDS pipe time hides under the ~5 us/tile load budget.
        #pragma unroll
        for (int rr = 0; rr < 8; ++rr) {
            const int row = rr * 8 + r0;
            tileT[lane64 * 4 + 0][row] = vbuf[rr].x;
            tileT[lane64 * 4 + 1][row] = vbuf[rr].y;
            tileT[lane64 * 4 + 2][row] = vbuf[rr].z;
            tileT[lane64 * 4 + 3][row] = vbuf[rr].w;
        }
        LDS_BARRIER();                     // tile visible; vmcnt NOT drained

        // ---- issue tile j+1 (regs free after commit); flies during scatter ----
        if (j + 1 < jmax) {
            const size_t v0 = (size_t)(bx + GX * (j + 1)) * VC;
            #pragma unroll
            for (int rr = 0; rr < 8; ++rr)
                vbuf[rr] = *reinterpret_cast<const float4*>(
                    &W_e[(size_t)(e0 + rr * 8 + r0) * VOCAB + v0 + lane64 * 4]);
        }

        // ---- scatter tile j: quarter-wave per token, float4 everywhere ----
        int nt = cnts[j];
        if (nt > LCAP) nt = LCAP;          // safety clamp (unreachable)
        const int ngroups = (nt + 3) >> 2;
        for (int g = w; g < ngroups; g += 8) {
            const int slot = g * 4 + q;
            if (slot < nt) {
                const int entry = list[j][slot];
                const int bs    = entry & 0xFFF;
                const int col   = entry >> 12;
                const int s     = bs & (SLEN - 1);
                // tileT read: bank = (col + 4*l16 + k) % 32, worst 2-way (free)
                const float v0 = tileT[col][l16 * 4 + 0];
                const float v1 = tileT[col][l16 * 4 + 1];
                const float v2 = tileT[col][l16 * 4 + 2];
                const float v3 = tileT[col][l16 * 4 + 3];
                const float4 wp = *reinterpret_cast<const float4*>(
                    &W_p[(size_t)s * EDIM + e0 + l16 * 4]);
                float4 r;
                r.x = v0 + wp.x; r.y = v1 + wp.y; r.z = v2 + wp.z; r.w = v3 + wp.w;
                *reinterpret_cast<float4*>(
                    &out[(size_t)bs * EDIM + e0 + l16 * 4]) = r;
            }
        }
        LDS_BARRIER();                     // scatter done; j+1 loads in flight
    }
}

extern "C" void kernel_launch(void* const* d_in, const int* in_sizes, int n_in,
                              void* d_out, int out_size, void* d_ws, size_t ws_size,
                              hipStream_t stream) {
    const int*   tokens = (const int*)d_in[0];
    const float* W_e    = (const float*)d_in[1];
    const float* W_p    = (const float*)d_in[2];
    float*       out    = (float*)d_out;

    dim3 grid(GX, NE);                     // 32 x 16 = 512 blocks, 2/CU (LDS-limited)
    fused_embed_kernel<<<grid, NTHR, 0, stream>>>(tokens, W_e, W_p, out);
}